// Round 1
// baseline (475.627 us; speedup 1.0000x reference)
//
#include <hip/hip_runtime.h>
#include <hip/hip_bf16.h>
#include <stdint.h>

#define NB 4
#define NK 64
#define NL 128
#define ND 768
#define NBK (NB*NK)        // 256
#define NROW (NBK*NL)      // 32768
#define LD2 (NL*ND)        // 98304
#define EPSF 1e-8f

typedef __bf16 bf16x8 __attribute__((ext_vector_type(8)));
typedef float  f32x4  __attribute__((ext_vector_type(4)));

// Row space r in [0, 2*NROW): [0,NROW) = ctx rows (bk=r>>7, l=r&127),
// [NROW,2*NROW) = ent rows. Returns float offset into context tensor.
__device__ __forceinline__ int row_off(int r) {
  if (r < NROW) return r*ND + (r >> 7)*LD2;
  int r2 = r - NROW;
  return r2*ND + (r2 >> 7)*LD2 + LD2;
}

// ---------------- K0: w1 -> w1t (transposed [e][k], bf16, bank-swizzled) ---
// Store granule g=k>>3 of row e at g' = g ^ (e&7) so the MFMA B-frag
// ds_read_b128 pattern (16 rows x 16B) spreads evenly across banks.
__global__ void k0_w1t(const float* __restrict__ w1, __bf16* __restrict__ w1t) {
  int idx = blockIdx.x*256 + threadIdx.x;   // < ND*ND
  int e = idx % ND, k = idx / ND;           // consecutive tid -> consecutive e (coalesced read)
  float v = w1[k*ND + e];
  int g = (k >> 3) ^ (e & 7);
  w1t[e*ND + g*8 + (k & 7)] = (__bf16)v;
}

// ---------------- K1: per-row L2 norms (one wave per row) ------------------
__global__ void k1_norms(const float* __restrict__ ctxall, float* __restrict__ norm) {
  int wave = threadIdx.x >> 6, lane = threadIdx.x & 63;
  int r = blockIdx.x*4 + wave;              // < 2*NROW
  const f32x4* p = (const f32x4*)(ctxall + row_off(r));
  float acc = 0.f;
  #pragma unroll
  for (int i = 0; i < 3; i++) {
    f32x4 v = p[i*64 + lane];
    acc += v[0]*v[0] + v[1]*v[1] + v[2]*v[2] + v[3]*v[3];
  }
  #pragma unroll
  for (int m = 1; m < 64; m <<= 1) acc += __shfl_xor(acc, m);
  if (lane == 0) norm[r] = sqrtf(acc);
}

// ---------------- K2: cosine scores + row argmax, f32 SGEMM per (b,k) ------
// 512 threads = 16 tr x 32 tc; each thread computes 8 rows x 4 cols.
__global__ __launch_bounds__(512) void k2_scores(
    const float* __restrict__ ctxall, const float* __restrict__ norm,
    int* __restrict__ amax) {
  __shared__ float at[16][128];   // k-major ctx tile
  __shared__ float bt[16][128];   // k-major ent tile
  int bk = blockIdx.x;
  const float* cbase = ctxall + bk*2*LD2;
  const float* ebase = cbase + LD2;
  int tid = threadIdx.x;
  int tr = tid >> 5, tc = tid & 31;
  float acc[8][4];
  #pragma unroll
  for (int j = 0; j < 8; j++)
    #pragma unroll
    for (int c = 0; c < 4; c++) acc[j][c] = 0.f;

  int srow = tid >> 2, skk = (tid & 3)*4;   // staging mapping: 4 f32/thread/array

  for (int k0 = 0; k0 < ND; k0 += 16) {
    f32x4 av = *(const f32x4*)(cbase + srow*ND + k0 + skk);
    f32x4 bv = *(const f32x4*)(ebase + srow*ND + k0 + skk);
    __syncthreads();                         // protect previous iter's reads
    #pragma unroll
    for (int j = 0; j < 4; j++) { at[skk+j][srow] = av[j]; bt[skk+j][srow] = bv[j]; }
    __syncthreads();
    #pragma unroll
    for (int kk = 0; kk < 16; kk++) {
      f32x4 a0 = *(const f32x4*)&at[kk][tr*8];
      f32x4 a1 = *(const f32x4*)&at[kk][tr*8 + 4];
      f32x4 b  = *(const f32x4*)&bt[kk][tc*4];
      #pragma unroll
      for (int j = 0; j < 4; j++)
        #pragma unroll
        for (int c = 0; c < 4; c++) {
          acc[j][c]   = fmaf(a0[j], b[c], acc[j][c]);
          acc[j+4][c] = fmaf(a1[j], b[c], acc[j+4][c]);
        }
    }
  }

  float en[4];
  #pragma unroll
  for (int c = 0; c < 4; c++) en[c] = norm[NROW + bk*NL + tc*4 + c];

  float bestv[8]; int besti[8];
  #pragma unroll
  for (int j = 0; j < 8; j++) {
    float cn = norm[bk*NL + tr*8 + j];
    bestv[j] = -3.0e38f; besti[j] = 0;
    #pragma unroll
    for (int c = 0; c < 4; c++) {
      float s = acc[j][c] / (cn*en[c] + EPSF);
      if (s > bestv[j]) { bestv[j] = s; besti[j] = tc*4 + c; }  // strict > keeps first max
    }
  }
  // reduce across the 32 tc lanes (masks < 32 stay within the tc group)
  #pragma unroll
  for (int off = 1; off < 32; off <<= 1) {
    #pragma unroll
    for (int j = 0; j < 8; j++) {
      float ov = __shfl_xor(bestv[j], off);
      int   oi = __shfl_xor(besti[j], off);
      if (ov > bestv[j] || (ov == bestv[j] && oi < besti[j])) { bestv[j] = ov; besti[j] = oi; }
    }
  }
  if (tc == 0) {
    #pragma unroll
    for (int j = 0; j < 8; j++) amax[bk*NL + tr*8 + j] = besti[j];
  }
}

// ---------------- K3: fused MLP value per row (bf16 MFMA) ------------------
// Block = 4 waves x 32 rows = 128 rows. A-frags (normalized rows, bf16) held
// in registers for full K=768. N-loop streams w1t 16-col tiles via
// global_load_lds; epilogue fuses relu + b1 + w2-dot (f32).
__global__ __launch_bounds__(256, 2) void k3_mlp(
    const float* __restrict__ ctxall, const float* __restrict__ norm,
    const __bf16* __restrict__ w1t, const float* __restrict__ b1,
    const float* __restrict__ w2, float* __restrict__ val) {
  __shared__ alignas(16) __bf16 btile[16*768];   // 24 KB w1t tile
  int tid = threadIdx.x;
  int wave = tid >> 6, lane = tid & 63;
  int quad = lane >> 4, eloc = lane & 15;
  int rbase = blockIdx.x*128 + wave*32;

  // Preload A fragments: lane holds A[m=lane&15][k=quad*8+j] per 32-wide kstep
  bf16x8 afrag[2][24];
  #pragma unroll
  for (int s = 0; s < 2; s++) {
    int r = rbase + s*16 + eloc;
    const float* src = ctxall + row_off(r);
    float rinv = 1.0f / norm[r];
    #pragma unroll
    for (int ks = 0; ks < 24; ks++) {
      const float* sp = src + ks*32 + quad*8;
      f32x4 v0 = *(const f32x4*)sp;
      f32x4 v1 = *(const f32x4*)(sp + 4);
      bf16x8 a;
      a[0] = (__bf16)(v0[0]*rinv); a[1] = (__bf16)(v0[1]*rinv);
      a[2] = (__bf16)(v0[2]*rinv); a[3] = (__bf16)(v0[3]*rinv);
      a[4] = (__bf16)(v1[0]*rinv); a[5] = (__bf16)(v1[1]*rinv);
      a[6] = (__bf16)(v1[2]*rinv); a[7] = (__bf16)(v1[3]*rinv);
      afrag[s][ks] = a;
    }
  }

  float oacc[2][4] = {{0,0,0,0},{0,0,0,0}};
  for (int nt = 0; nt < 48; nt++) {
    const __bf16* gsrc = w1t + nt*16*ND;     // contiguous 24 KB tile
    __syncthreads();                          // prior iter's ds_reads done
    #pragma unroll
    for (int i = 0; i < 6; i++) {
      __builtin_amdgcn_global_load_lds(
        (const __attribute__((address_space(1))) unsigned int*)(gsrc + (i*256 + tid)*8),
        (__attribute__((address_space(3))) unsigned int*)(btile + (i*256 + tid)*8),
        16, 0, 0);
    }
    __syncthreads();                          // drains vmcnt before consume

    f32x4 h0 = {0,0,0,0}, h1 = {0,0,0,0};
    #pragma unroll
    for (int ks = 0; ks < 24; ks++) {
      int g = ks*4 + quad;                    // 16B granule covering k=g*8..g*8+7
      bf16x8 bfrag = *(const bf16x8*)(btile + eloc*ND + ((g ^ (eloc & 7))*8));
      h0 = __builtin_amdgcn_mfma_f32_16x16x32_bf16(afrag[0][ks], bfrag, h0, 0, 0, 0);
      h1 = __builtin_amdgcn_mfma_f32_16x16x32_bf16(afrag[1][ks], bfrag, h1, 0, 0, 0);
    }
    // D layout: row = quad*4+rr, col(e_local) = lane&15
    float b1v = b1[nt*16 + eloc];
    float w2v = w2[nt*16 + eloc];
    #pragma unroll
    for (int rr = 0; rr < 4; rr++) {
      oacc[0][rr] += fmaxf(h0[rr] + b1v, 0.f) * w2v;
      oacc[1][rr] += fmaxf(h1[rr] + b1v, 0.f) * w2v;
    }
  }
  // sum over the 16 e-residue lanes
  #pragma unroll
  for (int m = 1; m < 16; m <<= 1)
    #pragma unroll
    for (int s = 0; s < 2; s++)
      #pragma unroll
      for (int rr = 0; rr < 4; rr++)
        oacc[s][rr] += __shfl_xor(oacc[s][rr], m);
  if (eloc == 0) {
    #pragma unroll
    for (int s = 0; s < 2; s++)
      #pragma unroll
      for (int rr = 0; rr < 4; rr++)
        val[rbase + s*16 + quad*4 + rr] = oacc[s][rr];
  }
}

// ---------------- K4: gather-add final output ------------------------------
__global__ void k4_out(const float* __restrict__ val, const int* __restrict__ amax,
                       const float* __restrict__ b2, float* __restrict__ out) {
  int i = blockIdx.x*256 + threadIdx.x;      // < NROW
  int bk = i >> 7;
  out[i] = val[i] + val[NROW + bk*NL + amax[i]] + 2.0f*b2[0];
}

extern "C" void kernel_launch(void* const* d_in, const int* in_sizes, int n_in,
                              void* d_out, int out_size, void* d_ws, size_t ws_size,
                              hipStream_t stream) {
  const float* ctxall = (const float*)d_in[0];
  const float* w1 = (const float*)d_in[1];
  const float* b1 = (const float*)d_in[2];
  const float* w2 = (const float*)d_in[3];
  const float* b2 = (const float*)d_in[4];
  float* out = (float*)d_out;

  char* ws = (char*)d_ws;
  float* norm = (float*)ws;                         // 2*NROW f32  = 262144 B
  int*   amax = (int*)(ws + 262144);                // NROW i32    = 131072 B
  float* val  = (float*)(ws + 262144 + 131072);     // 2*NROW f32  = 262144 B
  __bf16* w1t = (__bf16*)(ws + 655360);             // ND*ND bf16  = 1179648 B

  hipLaunchKernelGGL(k0_w1t,   dim3(ND*ND/256), dim3(256), 0, stream, w1, w1t);
  hipLaunchKernelGGL(k1_norms, dim3(2*NROW/4),  dim3(256), 0, stream, ctxall, norm);
  hipLaunchKernelGGL(k2_scores,dim3(NBK),       dim3(512), 0, stream, ctxall, norm, amax);
  hipLaunchKernelGGL(k3_mlp,   dim3(2*NROW/128),dim3(256), 0, stream, ctxall, norm, w1t, b1, w2, val);
  hipLaunchKernelGGL(k4_out,   dim3(NROW/256),  dim3(256), 0, stream, val, amax, b2, out);
}

// Round 2
// 424.222 us; speedup vs baseline: 1.1212x; 1.1212x over previous
//
#include <hip/hip_runtime.h>
#include <hip/hip_bf16.h>
#include <stdint.h>

#define NB 4
#define NK 64
#define NL 128
#define ND 768
#define NBK (NB*NK)        // 256
#define NROW (NBK*NL)      // 32768
#define LD2 (NL*ND)        // 98304
#define EPSF 1e-8f

typedef __bf16 bf16x8 __attribute__((ext_vector_type(8)));
typedef float  f32x4  __attribute__((ext_vector_type(4)));

// Row space r in [0, 2*NROW): [0,NROW) = ctx rows (bk=r>>7, l=r&127),
// [NROW,2*NROW) = ent rows. Returns float offset into context tensor.
__device__ __forceinline__ int row_off(int r) {
  if (r < NROW) return r*ND + (r >> 7)*LD2;
  int r2 = r - NROW;
  return r2*ND + (r2 >> 7)*LD2 + LD2;
}

// ---------------- K0: w1 -> w1t (transposed [e][k], bf16, bank-swizzled) ---
// Granule g=k>>3 of row e stored at g' = g ^ (e&7): spreads k3's B-frag
// ds_read_b128 across all bank groups. XOR permutes within an aligned 128 B
// window, so coalesced 16 B stores stay within contiguous 128 B segments.
// LDS transpose: coalesced f32x4 reads, 16 B granule stores.
__global__ __launch_bounds__(256) void k0_w1t(const float* __restrict__ w1,
                                              __bf16* __restrict__ w1t) {
  __shared__ float tile[64][68];               // [k][e], +4 pad (16B-aligned rows)
  int kb = (blockIdx.x / 12) * 64, eb = (blockIdx.x % 12) * 64;
  int t = threadIdx.x;
  // stage: 64 rows(k) x 64 cols(e) f32; thread -> row t>>2, 16-float chunk t&3
  int r = t >> 2, c0 = (t & 3) * 16;
  #pragma unroll
  for (int j = 0; j < 4; j++) {
    f32x4 v = *(const f32x4*)(w1 + (kb + r)*ND + eb + c0 + j*4);
    *(f32x4*)&tile[r][c0 + j*4] = v;
  }
  __syncthreads();
  // emit: thread -> e = t&63, granule pair gi = t>>6
  int e = t & 63, gi = t >> 6;
  int eg = eb + e;
  #pragma unroll
  for (int g2 = 0; g2 < 2; g2++) {
    int g = gi*2 + g2;                         // local granule 0..7 (k = g*8..)
    bf16x8 o;
    #pragma unroll
    for (int j = 0; j < 8; j++) o[j] = (__bf16)tile[g*8 + j][e];
    int G = (kb >> 3) + (g ^ (eg & 7));        // kb/8 is 8-aligned
    *(bf16x8*)(w1t + eg*ND + G*8) = o;
  }
}

// ---------------- K2: cosine scores + argmax + fused norms -----------------
// grid = 512: (bk, row-half). 256 threads compute 64 rows x 128 cols, 8x4
// per thread. Double-buffered LDS (1 barrier/tile). Norms accumulated during
// staging, block-reduced at the end, written to ws for k3.
__global__ __launch_bounds__(256) void k2_scores(
    const float* __restrict__ ctxall, float* __restrict__ norm,
    int* __restrict__ amax) {
  __shared__ float at[2][16][68];    // k-major ctx tile (+4 pad)
  __shared__ float bt[2][16][132];   // k-major ent tile (+4 pad)
  __shared__ float red[256];
  __shared__ float cnorm[64], enorm[128];
  int bk = blockIdx.x >> 1, half = blockIdx.x & 1;
  const float* cbase = ctxall + bk*2*LD2 + half*64*ND;
  const float* ebase = ctxall + bk*2*LD2 + LD2;
  int tid = threadIdx.x;
  int tr = tid >> 5, tc = tid & 31;            // 8 rows x 4 cols per thread
  int ar = tid >> 2, ak = (tid & 3)*4;         // a-staging: row, k-offset
  int br = tid >> 1, bkk = (tid & 1)*8;        // b-staging: row, k-offset

  float acc[8][4];
  #pragma unroll
  for (int j = 0; j < 8; j++)
    #pragma unroll
    for (int c = 0; c < 4; c++) acc[j][c] = 0.f;
  float sqa = 0.f, sqb = 0.f;

  // prologue: load tile 0
  f32x4 av  = *(const f32x4*)(cbase + ar*ND + ak);
  f32x4 bv0 = *(const f32x4*)(ebase + br*ND + bkk);
  f32x4 bv1 = *(const f32x4*)(ebase + br*ND + bkk + 4);

  int p = 0;
  for (int t = 0; t < 48; t++) {
    #pragma unroll
    for (int j = 0; j < 4; j++) { at[p][ak+j][ar] = av[j];     sqa += av[j]*av[j]; }
    #pragma unroll
    for (int j = 0; j < 4; j++) { bt[p][bkk+j][br] = bv0[j];   sqb += bv0[j]*bv0[j]; }
    #pragma unroll
    for (int j = 0; j < 4; j++) { bt[p][bkk+4+j][br] = bv1[j]; sqb += bv1[j]*bv1[j]; }
    __syncthreads();
    if (t < 47) {                              // prefetch next tile (latency hidden by compute)
      int k0 = (t+1)*16;
      av  = *(const f32x4*)(cbase + ar*ND + k0 + ak);
      bv0 = *(const f32x4*)(ebase + br*ND + k0 + bkk);
      bv1 = *(const f32x4*)(ebase + br*ND + k0 + bkk + 4);
    }
    #pragma unroll
    for (int kk = 0; kk < 16; kk++) {
      f32x4 a0 = *(const f32x4*)&at[p][kk][tr*8];
      f32x4 a1 = *(const f32x4*)&at[p][kk][tr*8 + 4];
      f32x4 b  = *(const f32x4*)&bt[p][kk][tc*4];
      #pragma unroll
      for (int j = 0; j < 4; j++)
        #pragma unroll
        for (int c = 0; c < 4; c++) {
          acc[j][c]   = fmaf(a0[j], b[c], acc[j][c]);
          acc[j+4][c] = fmaf(a1[j], b[c], acc[j+4][c]);
        }
    }
    p ^= 1;
  }

  // fused norms: block-reduce the staging partial sums
  red[tid] = sqa; __syncthreads();
  if (tid < 64) {
    float s = red[tid*4] + red[tid*4+1] + red[tid*4+2] + red[tid*4+3];
    float n = sqrtf(s);
    cnorm[tid] = n;
    norm[bk*NL + half*64 + tid] = n;
  }
  __syncthreads();
  red[tid] = sqb; __syncthreads();
  if (tid < 128) {
    float s = red[tid*2] + red[tid*2+1];
    float n = sqrtf(s);
    enorm[tid] = n;
    if (half == 0) norm[NROW + bk*NL + tid] = n;   // ent norms written once
  }
  __syncthreads();

  float en[4];
  #pragma unroll
  for (int c = 0; c < 4; c++) en[c] = enorm[tc*4 + c];

  float bestv[8]; int besti[8];
  #pragma unroll
  for (int j = 0; j < 8; j++) {
    float cn = cnorm[tr*8 + j];
    bestv[j] = -3.0e38f; besti[j] = 0;
    #pragma unroll
    for (int c = 0; c < 4; c++) {
      float s = acc[j][c] / (cn*en[c] + EPSF);
      if (s > bestv[j]) { bestv[j] = s; besti[j] = tc*4 + c; }
    }
  }
  // reduce across the 32 tc lanes (xor masks < 32 stay within the tc group)
  #pragma unroll
  for (int off = 1; off < 32; off <<= 1) {
    #pragma unroll
    for (int j = 0; j < 8; j++) {
      float ov = __shfl_xor(bestv[j], off);
      int   oi = __shfl_xor(besti[j], off);
      if (ov > bestv[j] || (ov == bestv[j] && oi < besti[j])) { bestv[j] = ov; besti[j] = oi; }
    }
  }
  if (tc == 0) {
    #pragma unroll
    for (int j = 0; j < 8; j++) amax[bk*NL + half*64 + tr*8 + j] = besti[j];
  }
}

// ---------------- K3: fused MLP value per row (bf16 MFMA) ------------------
// Block = 4 waves x 32 rows = 128 rows. A-frags (normalized rows, bf16) held
// in registers for full K=768. N-loop streams w1t 16-col tiles via
// global_load_lds; epilogue fuses relu + b1 + w2-dot (f32).
__global__ __launch_bounds__(256, 2) void k3_mlp(
    const float* __restrict__ ctxall, const float* __restrict__ norm,
    const __bf16* __restrict__ w1t, const float* __restrict__ b1,
    const float* __restrict__ w2, float* __restrict__ val) {
  __shared__ alignas(16) __bf16 btile[16*768];   // 24 KB w1t tile
  int tid = threadIdx.x;
  int wave = tid >> 6, lane = tid & 63;
  int quad = lane >> 4, eloc = lane & 15;
  int rbase = blockIdx.x*128 + wave*32;

  // Preload A fragments: lane holds A[m=lane&15][k=quad*8+j] per 32-wide kstep
  bf16x8 afrag[2][24];
  #pragma unroll
  for (int s = 0; s < 2; s++) {
    int r = rbase + s*16 + eloc;
    const float* src = ctxall + row_off(r);
    float rinv = 1.0f / norm[r];
    #pragma unroll
    for (int ks = 0; ks < 24; ks++) {
      const float* sp = src + ks*32 + quad*8;
      f32x4 v0 = *(const f32x4*)sp;
      f32x4 v1 = *(const f32x4*)(sp + 4);
      bf16x8 a;
      a[0] = (__bf16)(v0[0]*rinv); a[1] = (__bf16)(v0[1]*rinv);
      a[2] = (__bf16)(v0[2]*rinv); a[3] = (__bf16)(v0[3]*rinv);
      a[4] = (__bf16)(v1[0]*rinv); a[5] = (__bf16)(v1[1]*rinv);
      a[6] = (__bf16)(v1[2]*rinv); a[7] = (__bf16)(v1[3]*rinv);
      afrag[s][ks] = a;
    }
  }

  float oacc[2][4] = {{0,0,0,0},{0,0,0,0}};
  for (int nt = 0; nt < 48; nt++) {
    const __bf16* gsrc = w1t + nt*16*ND;     // contiguous 24 KB tile
    __syncthreads();                          // prior iter's ds_reads done
    #pragma unroll
    for (int i = 0; i < 6; i++) {
      __builtin_amdgcn_global_load_lds(
        (const __attribute__((address_space(1))) unsigned int*)(gsrc + (i*256 + tid)*8),
        (__attribute__((address_space(3))) unsigned int*)(btile + (i*256 + tid)*8),
        16, 0, 0);
    }
    __syncthreads();                          // drains vmcnt before consume

    f32x4 h0 = {0,0,0,0}, h1 = {0,0,0,0};
    #pragma unroll
    for (int ks = 0; ks < 24; ks++) {
      int g = ks*4 + quad;                    // 16B granule covering k=g*8..g*8+7
      bf16x8 bfrag = *(const bf16x8*)(btile + eloc*ND + ((g ^ (eloc & 7))*8));
      h0 = __builtin_amdgcn_mfma_f32_16x16x32_bf16(afrag[0][ks], bfrag, h0, 0, 0, 0);
      h1 = __builtin_amdgcn_mfma_f32_16x16x32_bf16(afrag[1][ks], bfrag, h1, 0, 0, 0);
    }
    // D layout: row = quad*4+rr, col(e_local) = lane&15
    float b1v = b1[nt*16 + eloc];
    float w2v = w2[nt*16 + eloc];
    #pragma unroll
    for (int rr = 0; rr < 4; rr++) {
      oacc[0][rr] += fmaxf(h0[rr] + b1v, 0.f) * w2v;
      oacc[1][rr] += fmaxf(h1[rr] + b1v, 0.f) * w2v;
    }
  }
  // sum over the 16 e-residue lanes
  #pragma unroll
  for (int m = 1; m < 16; m <<= 1)
    #pragma unroll
    for (int s = 0; s < 2; s++)
      #pragma unroll
      for (int rr = 0; rr < 4; rr++)
        oacc[s][rr] += __shfl_xor(oacc[s][rr], m);
  if (eloc == 0) {
    #pragma unroll
    for (int s = 0; s < 2; s++)
      #pragma unroll
      for (int rr = 0; rr < 4; rr++)
        val[rbase + s*16 + quad*4 + rr] = oacc[s][rr];
  }
}

// ---------------- K4: gather-add final output ------------------------------
__global__ void k4_out(const float* __restrict__ val, const int* __restrict__ amax,
                       const float* __restrict__ b2, float* __restrict__ out) {
  int i = blockIdx.x*256 + threadIdx.x;      // < NROW
  int bk = i >> 7;
  out[i] = val[i] + val[NROW + bk*NL + amax[i]] + 2.0f*b2[0];
}

extern "C" void kernel_launch(void* const* d_in, const int* in_sizes, int n_in,
                              void* d_out, int out_size, void* d_ws, size_t ws_size,
                              hipStream_t stream) {
  const float* ctxall = (const float*)d_in[0];
  const float* w1 = (const float*)d_in[1];
  const float* b1 = (const float*)d_in[2];
  const float* w2 = (const float*)d_in[3];
  const float* b2 = (const float*)d_in[4];
  float* out = (float*)d_out;

  char* ws = (char*)d_ws;
  float* norm = (float*)ws;                         // 2*NROW f32  = 262144 B
  int*   amax = (int*)(ws + 262144);                // NROW i32    = 131072 B
  float* val  = (float*)(ws + 262144 + 131072);     // 2*NROW f32  = 262144 B
  __bf16* w1t = (__bf16*)(ws + 655360);             // ND*ND bf16  = 1179648 B

  hipLaunchKernelGGL(k0_w1t,   dim3(144),         dim3(256), 0, stream, w1, w1t);
  hipLaunchKernelGGL(k2_scores,dim3(2*NBK),       dim3(256), 0, stream, ctxall, norm, amax);
  hipLaunchKernelGGL(k3_mlp,   dim3(2*NROW/128),  dim3(256), 0, stream, ctxall, norm, w1t, b1, w2, val);
  hipLaunchKernelGGL(k4_out,   dim3(NROW/256),    dim3(256), 0, stream, val, amax, b2, out);
}

// Round 3
// 395.850 us; speedup vs baseline: 1.2015x; 1.0717x over previous
//
#include <hip/hip_runtime.h>
#include <hip/hip_bf16.h>
#include <stdint.h>

#define NB 4
#define NK 64
#define NL 128
#define ND 768
#define NBK (NB*NK)        // 256
#define NROW (NBK*NL)      // 32768
#define LD2 (NL*ND)        // 98304
#define EPSF 1e-8f
#define THETA 2e-3f        // candidate window on dot*einv scale (~75 sigma of split-bf16 error)
#define CAP 16384          // candidate list capacity (expect ~300)

typedef __bf16 bf16x8 __attribute__((ext_vector_type(8)));
typedef float  f32x4  __attribute__((ext_vector_type(4)));

// Row space r in [0, 2*NROW): [0,NROW) = ctx rows (bk=r>>7, l=r&127),
// [NROW,2*NROW) = ent rows. Returns float offset into context tensor.
__device__ __forceinline__ int row_off(int r) {
  if (r < NROW) return r*ND + (r >> 7)*LD2;
  int r2 = r - NROW;
  return r2*ND + (r2 >> 7)*LD2 + LD2;
}

// ---------------- K0: w1 -> w1t transpose + zero-init of fixup state -------
__global__ __launch_bounds__(256) void k0_w1t(const float* __restrict__ w1,
                                              __bf16* __restrict__ w1t,
                                              unsigned long long* __restrict__ amax2,
                                              unsigned* __restrict__ cntg) {
  __shared__ float tile[64][68];               // [k][e], +4 pad
  int idx = blockIdx.x*256 + threadIdx.x;
  if (idx < NROW) amax2[idx] = 0ull;           // fixup keys zeroed every launch
  if (idx == 0) *cntg = 0u;
  int kb = (blockIdx.x / 12) * 64, eb = (blockIdx.x % 12) * 64;
  int t = threadIdx.x;
  int r = t >> 2, c0 = (t & 3) * 16;
  #pragma unroll
  for (int j = 0; j < 4; j++) {
    f32x4 v = *(const f32x4*)(w1 + (kb + r)*ND + eb + c0 + j*4);
    *(f32x4*)&tile[r][c0 + j*4] = v;
  }
  __syncthreads();
  int e = t & 63, gi = t >> 6;
  int eg = eb + e;
  #pragma unroll
  for (int g2 = 0; g2 < 2; g2++) {
    int g = gi*2 + g2;
    bf16x8 o;
    #pragma unroll
    for (int j = 0; j < 8; j++) o[j] = (__bf16)tile[g*8 + j][e];
    int G = (kb >> 3) + (g ^ (eg & 7));        // bank swizzle for k3's frag reads
    *(bf16x8*)(w1t + eg*ND + G*8) = o;
  }
}

// split f32x4 into truncated-bf16 hi (packed pair uints) and exact-remainder
// lo (truncated to bf16); accumulate sum of squares of the f32 values.
__device__ __forceinline__ void cvt4(f32x4 v, unsigned& hp0, unsigned& hp1,
                                     unsigned& lp0, unsigned& lp1, float& sq) {
  unsigned u0 = __float_as_uint(v[0]), u1 = __float_as_uint(v[1]);
  unsigned u2 = __float_as_uint(v[2]), u3 = __float_as_uint(v[3]);
  hp0 = (u1 & 0xffff0000u) | (u0 >> 16);
  hp1 = (u3 & 0xffff0000u) | (u2 >> 16);
  float l0 = v[0] - __uint_as_float(u0 & 0xffff0000u);   // exact (Sterbenz)
  float l1 = v[1] - __uint_as_float(u1 & 0xffff0000u);
  float l2 = v[2] - __uint_as_float(u2 & 0xffff0000u);
  float l3 = v[3] - __uint_as_float(u3 & 0xffff0000u);
  lp0 = (__float_as_uint(l1) & 0xffff0000u) | (__float_as_uint(l0) >> 16);
  lp1 = (__float_as_uint(l3) & 0xffff0000u) | (__float_as_uint(l2) >> 16);
  sq += v[0]*v[0] + v[1]*v[1] + v[2]*v[2] + v[3]*v[3];
}

// ---------------- K2a: MFMA cosine screen + argmax + norms + candidates ----
// One block per bk: 128 ctx x 128 ent x K=768. 512 thr = 8 waves, wave w owns
// rows w*16..+15, all 128 cols (8 col-tiles), acc = 3-product split-bf16 sum.
// Staging: thread (mat,row,khalf) converts its 16-k f32 seg to hi/lo bf16,
// double-buffered Kt=32 tiles (one barrier/step). Norm = per-thread sq sums.
__global__ __launch_bounds__(512) void k2a_screen(
    const float* __restrict__ ctxall, float* __restrict__ norm,
    int* __restrict__ amax, unsigned* __restrict__ cntg,
    unsigned* __restrict__ list) {
  __shared__ alignas(16) __bf16 tiles[2][4][128*32];   // [buf][ahi,alo,bhi,blo]
  __shared__ float einv_s[128];
  int bk = blockIdx.x;
  int t = threadIdx.x;
  int mat = t >> 8, row = (t >> 1) & 127, kh = (t & 1) * 16;
  const float* src = ctxall + bk*2*LD2 + mat*LD2 + row*ND + kh;
  int w = t >> 6, lane = t & 63, quad = lane >> 4, eloc = lane & 15;

  f32x4 pv[4];
  #pragma unroll
  for (int i = 0; i < 4; i++) pv[i] = *(const f32x4*)(src + i*4);
  float sq = 0.f;
  f32x4 acc[8];
  #pragma unroll
  for (int ct = 0; ct < 8; ct++) acc[ct] = (f32x4){0,0,0,0};

  int p = 0;
  for (int kt = 0; kt < 24; kt++) {
    // convert current prefetch regs -> LDS[p]
    unsigned h0,h1,h2,h3, l0,l1,l2,l3;
    cvt4(pv[0], h0, h1, l0, l1, sq);
    cvt4(pv[1], h2, h3, l2, l3, sq);
    __bf16* hdst = &tiles[p][2*mat  ][row*32 + kh];
    __bf16* ldst = &tiles[p][2*mat+1][row*32 + kh];
    *(uint4*)hdst = make_uint4(h0,h1,h2,h3);
    *(uint4*)ldst = make_uint4(l0,l1,l2,l3);
    cvt4(pv[2], h0, h1, l0, l1, sq);
    cvt4(pv[3], h2, h3, l2, l3, sq);
    *((uint4*)hdst + 1) = make_uint4(h0,h1,h2,h3);
    *((uint4*)ldst + 1) = make_uint4(l0,l1,l2,l3);
    __syncthreads();
    if (kt < 23) {                             // prefetch next Kt (flies over compute)
      const float* s2 = src + (kt+1)*32;
      #pragma unroll
      for (int i = 0; i < 4; i++) pv[i] = *(const f32x4*)(s2 + i*4);
    }
    // compute: A-frag rows w*16+eloc, k=quad*8+j  (layout verified by k3 pass)
    bf16x8 ah = *(const bf16x8*)&tiles[p][0][(w*16+eloc)*32 + quad*8];
    bf16x8 al = *(const bf16x8*)&tiles[p][1][(w*16+eloc)*32 + quad*8];
    #pragma unroll
    for (int ct = 0; ct < 8; ct++) {
      bf16x8 bh = *(const bf16x8*)&tiles[p][2][(ct*16+eloc)*32 + quad*8];
      bf16x8 bl = *(const bf16x8*)&tiles[p][3][(ct*16+eloc)*32 + quad*8];
      acc[ct] = __builtin_amdgcn_mfma_f32_16x16x32_bf16(al, bh, acc[ct], 0, 0, 0);
      acc[ct] = __builtin_amdgcn_mfma_f32_16x16x32_bf16(ah, bl, acc[ct], 0, 0, 0);
      acc[ct] = __builtin_amdgcn_mfma_f32_16x16x32_bf16(ah, bh, acc[ct], 0, 0, 0);
    }
    p ^= 1;
  }

  // norms: thread pair (t, t^1) holds the two k-halves of one row
  float stot = sq + __shfl_xor(sq, 1);
  if ((t & 1) == 0) {
    float n = sqrtf(stot);
    if (mat == 0) norm[bk*NL + row] = n;
    else { norm[NROW + bk*NL + row] = n; einv_s[row] = 1.0f / n; }
  }
  __syncthreads();

  // epilogue: per-row argmax of acc*einv + theta-window candidate push
  #pragma unroll
  for (int rr = 0; rr < 4; rr++) {
    float sc[8];
    float best = -3.0e38f; int bcol = 0;
    #pragma unroll
    for (int ct = 0; ct < 8; ct++) {
      sc[ct] = acc[ct][rr] * einv_s[ct*16 + eloc];
      int col = ct*16 + eloc;
      if (sc[ct] > best) { best = sc[ct]; bcol = col; }
    }
    #pragma unroll
    for (int m = 1; m < 16; m <<= 1) {
      float ov = __shfl_xor(best, m);
      int   oc = __shfl_xor(bcol, m);
      if (ov > best || (ov == best && oc < bcol)) { best = ov; bcol = oc; }
    }
    int grow = bk*NL + w*16 + quad*4 + rr;
    if (eloc == 0) amax[grow] = bcol;
    int cnt = 0;
    #pragma unroll
    for (int ct = 0; ct < 8; ct++) cnt += (sc[ct] >= best - THETA) ? 1 : 0;
    #pragma unroll
    for (int m = 1; m < 16; m <<= 1) cnt += __shfl_xor(cnt, m);
    if (cnt >= 2) {                            // near-tie: exact rescore needed
      #pragma unroll
      for (int ct = 0; ct < 8; ct++) {
        if (sc[ct] >= best - THETA) {
          unsigned idx = atomicAdd(cntg, 1u);
          if (idx < CAP) list[idx] = ((unsigned)grow << 7) | (unsigned)(ct*16 + eloc);
        }
      }
    }
  }
}

// ---------------- K2b: exact f32 rescore of near-tie candidates ------------
// One wave per candidate: f32 dot + reference denom; atomicMax on packed
// (ordered-score, 127-col) key so ties resolve to the lowest column.
__global__ __launch_bounds__(256) void k2b_rescore(
    const float* __restrict__ ctxall, const float* __restrict__ norm,
    const unsigned* __restrict__ cntg, const unsigned* __restrict__ list,
    unsigned long long* __restrict__ amax2) {
  unsigned n = *cntg; if (n > CAP) n = CAP;
  int lane = threadIdx.x & 63;
  unsigned wv = blockIdx.x*4 + (threadIdx.x >> 6);
  for (unsigned e = wv; e < n; e += 256) {
    unsigned ent = list[e];
    int row = (int)(ent >> 7), col = (int)(ent & 127);
    int bk = row >> 7;
    const float* a = ctxall + row_off(row);
    const float* b = ctxall + bk*2*LD2 + LD2 + col*ND;
    float d = 0.f;
    #pragma unroll
    for (int i = 0; i < 3; i++) {
      f32x4 va = *(const f32x4*)(a + lane*12 + i*4);
      f32x4 vb = *(const f32x4*)(b + lane*12 + i*4);
      d += va[0]*vb[0] + va[1]*vb[1] + va[2]*vb[2] + va[3]*vb[3];
    }
    #pragma unroll
    for (int m = 1; m < 64; m <<= 1) d += __shfl_xor(d, m);
    if (lane == 0) {
      float cn = norm[row], en = norm[NROW + bk*NL + col];
      float s = d / (cn*en + EPSF);
      unsigned su = __float_as_uint(s);
      unsigned ord = (su & 0x80000000u) ? ~su : (su | 0x80000000u);
      unsigned long long key = ((unsigned long long)ord << 32) | (unsigned)(127 - col);
      atomicMax(&amax2[row], key);
    }
  }
}

// ---------------- K3: fused MLP value per row (bf16 MFMA, dbuf btile) ------
__global__ __launch_bounds__(256, 2) void k3_mlp(
    const float* __restrict__ ctxall, const float* __restrict__ norm,
    const __bf16* __restrict__ w1t, const float* __restrict__ b1,
    const float* __restrict__ w2, float* __restrict__ val) {
  __shared__ alignas(16) __bf16 btile[2][16*768];   // 2 x 24 KB w1t tiles
  int tid = threadIdx.x;
  int wave = tid >> 6, lane = tid & 63;
  int quad = lane >> 4, eloc = lane & 15;
  int rbase = blockIdx.x*128 + wave*32;

  // issue nt=0 stage immediately; it overlaps the (long) A-preload below
  #pragma unroll
  for (int i = 0; i < 6; i++) {
    __builtin_amdgcn_global_load_lds(
      (const __attribute__((address_space(1))) unsigned int*)(w1t + (i*256 + tid)*8),
      (__attribute__((address_space(3))) unsigned int*)(&btile[0][0] + (i*256 + tid)*8),
      16, 0, 0);
  }

  // Preload A fragments: lane holds A[m=lane&15][k=quad*8+j] per 32-wide kstep
  bf16x8 afrag[2][24];
  #pragma unroll
  for (int s = 0; s < 2; s++) {
    int r = rbase + s*16 + eloc;
    const float* src = ctxall + row_off(r);
    float rinv = 1.0f / norm[r];
    #pragma unroll
    for (int ks = 0; ks < 24; ks++) {
      const float* sp = src + ks*32 + quad*8;
      f32x4 v0 = *(const f32x4*)sp;
      f32x4 v1 = *(const f32x4*)(sp + 4);
      bf16x8 a;
      a[0] = (__bf16)(v0[0]*rinv); a[1] = (__bf16)(v0[1]*rinv);
      a[2] = (__bf16)(v0[2]*rinv); a[3] = (__bf16)(v0[3]*rinv);
      a[4] = (__bf16)(v1[0]*rinv); a[5] = (__bf16)(v1[1]*rinv);
      a[6] = (__bf16)(v1[2]*rinv); a[7] = (__bf16)(v1[3]*rinv);
      afrag[s][ks] = a;
    }
  }

  float oacc[2][4] = {{0,0,0,0},{0,0,0,0}};
  int p = 0;
  for (int nt = 0; nt < 48; nt++) {
    __syncthreads();                          // drains btile[p] loads (vmcnt0)
    if (nt < 47) {                            // prefetch nt+1 into other buffer
      const __bf16* gsrc = w1t + (nt+1)*16*ND;
      #pragma unroll
      for (int i = 0; i < 6; i++) {
        __builtin_amdgcn_global_load_lds(
          (const __attribute__((address_space(1))) unsigned int*)(gsrc + (i*256 + tid)*8),
          (__attribute__((address_space(3))) unsigned int*)(&btile[p^1][0] + (i*256 + tid)*8),
          16, 0, 0);
      }
    }
    f32x4 h0 = {0,0,0,0}, h1 = {0,0,0,0};
    #pragma unroll
    for (int ks = 0; ks < 24; ks++) {
      int g = ks*4 + quad;
      bf16x8 bfrag = *(const bf16x8*)(&btile[p][0] + eloc*ND + ((g ^ (eloc & 7))*8));
      h0 = __builtin_amdgcn_mfma_f32_16x16x32_bf16(afrag[0][ks], bfrag, h0, 0, 0, 0);
      h1 = __builtin_amdgcn_mfma_f32_16x16x32_bf16(afrag[1][ks], bfrag, h1, 0, 0, 0);
    }
    float b1v = b1[nt*16 + eloc];
    float w2v = w2[nt*16 + eloc];
    #pragma unroll
    for (int rr = 0; rr < 4; rr++) {
      oacc[0][rr] += fmaxf(h0[rr] + b1v, 0.f) * w2v;
      oacc[1][rr] += fmaxf(h1[rr] + b1v, 0.f) * w2v;
    }
    p ^= 1;
  }
  #pragma unroll
  for (int m = 1; m < 16; m <<= 1)
    #pragma unroll
    for (int s = 0; s < 2; s++)
      #pragma unroll
      for (int rr = 0; rr < 4; rr++)
        oacc[s][rr] += __shfl_xor(oacc[s][rr], m);
  if (eloc == 0) {
    #pragma unroll
    for (int s = 0; s < 2; s++)
      #pragma unroll
      for (int rr = 0; rr < 4; rr++)
        val[rbase + s*16 + quad*4 + rr] = oacc[s][rr];
  }
}

// ---------------- K4: gather-add final output (with fixup override) --------
__global__ void k4_out(const float* __restrict__ val, const int* __restrict__ amax,
                       const unsigned long long* __restrict__ amax2,
                       const float* __restrict__ b2, float* __restrict__ out) {
  int i = blockIdx.x*256 + threadIdx.x;      // < NROW
  int bk = i >> 7;
  unsigned long long k = amax2[i];
  int a = k ? (127 - (int)(k & 127ull)) : amax[i];
  out[i] = val[i] + val[NROW + bk*NL + a] + 2.0f*b2[0];
}

extern "C" void kernel_launch(void* const* d_in, const int* in_sizes, int n_in,
                              void* d_out, int out_size, void* d_ws, size_t ws_size,
                              hipStream_t stream) {
  const float* ctxall = (const float*)d_in[0];
  const float* w1 = (const float*)d_in[1];
  const float* b1 = (const float*)d_in[2];
  const float* w2 = (const float*)d_in[3];
  const float* b2 = (const float*)d_in[4];
  float* out = (float*)d_out;

  char* ws = (char*)d_ws;
  float*    norm = (float*)ws;                        // [0, 262144)
  int*      amax = (int*)(ws + 262144);               // [262144, 393216)
  float*    val  = (float*)(ws + 393216);             // [393216, 655360)
  __bf16*   w1t  = (__bf16*)(ws + 655360);            // [655360, 1835008)
  unsigned long long* amax2 = (unsigned long long*)(ws + 1835008);  // 256 KB
  unsigned* cntg = (unsigned*)(ws + 2097152);         // 4 B
  unsigned* list = (unsigned*)(ws + 2097156);         // 64 KB

  hipLaunchKernelGGL(k0_w1t,     dim3(144),        dim3(256), 0, stream, w1, w1t, amax2, cntg);
  hipLaunchKernelGGL(k2a_screen, dim3(NBK),        dim3(512), 0, stream, ctxall, norm, amax, cntg, list);
  hipLaunchKernelGGL(k2b_rescore,dim3(64),         dim3(256), 0, stream, ctxall, norm, cntg, list, amax2);
  hipLaunchKernelGGL(k3_mlp,     dim3(2*NROW/128), dim3(256), 0, stream, ctxall, norm, w1t, b1, w2, val);
  hipLaunchKernelGGL(k4_out,     dim3(NROW/256),   dim3(256), 0, stream, val, amax, amax2, b2, out);
}